// Round 14
// baseline (312.820 us; speedup 1.0000x reference)
//
#include <hip/hip_runtime.h>
#include <hip/hip_bf16.h>
#include <cstdint>
#include <cstddef>

typedef __bf16 bf16_t;
typedef __attribute__((ext_vector_type(4))) __bf16 bf16x4;
typedef __attribute__((ext_vector_type(8))) __bf16 bf16x8;
typedef __attribute__((ext_vector_type(4))) float f32x4;

#define S_ 2048
#define H_ 16
#define NTOK 4096

__device__ __forceinline__ f32x4 mfma16x16(bf16x8 a, bf16x8 b, f32x4 c) {
  return __builtin_amdgcn_mfma_f32_16x16x32_bf16(a, b, c, 0, 0, 0);
}
__device__ __forceinline__ bf16x8 load8(const bf16_t* p) {
  return *reinterpret_cast<const bf16x8*>(p);
}
__device__ __forceinline__ void load_lds16(const void* g, void* l) {
  __builtin_amdgcn_global_load_lds(
      (const __attribute__((address_space(1))) uint32_t*)g,
      (__attribute__((address_space(3))) uint32_t*)l, 16, 0, 0);
}

// ---------------- prep kernels ----------------

__global__ void cast_bf16_k(const float* __restrict__ in, bf16_t* __restrict__ out, int n) {
  int idx = blockIdx.x * 256 + threadIdx.x;
  int i4 = idx * 4;
  if (i4 >= n) return;
  float4 v = *reinterpret_cast<const float4*>(in + i4);
  out[i4 + 0] = (bf16_t)v.x;
  out[i4 + 1] = (bf16_t)v.y;
  out[i4 + 2] = (bf16_t)v.z;
  out[i4 + 3] = (bf16_t)v.w;
}

__global__ void rope_tables_k(float* __restrict__ cosT, float* __restrict__ sinT) {
  int idx = blockIdx.x * 256 + threadIdx.x;
  if (idx >= S_ * 32) return;
  int s = idx >> 5, i = idx & 31;
  float inv = powf(10000.0f, -(2.0f * (float)i) / 64.0f);
  float fr = (float)s * inv;
  cosT[idx] = cosf(fr);
  sinT[idx] = sinf(fr);
}

// merged transpose+cast: in K x Nsrc (f32) -> out Nout x K (bf16).
// perm==1 (Wkvb job): output row n maps to src col f(n) so the kv GEMM's N axis
// becomes [16*64 k_nope | 16*128 v]; per 32-col block the src stays contiguous.
struct TDesc {
  const float* src;
  bf16_t* dst;
  int K, Nsrc, bxc, off, perm;
};
struct TDesc5 {
  TDesc d[5];
};

__global__ void transpose_cast_multi_k(TDesc5 ds) {
  __shared__ float tile[32][33];
  const int bid = blockIdx.x;
  int i = 0;
#pragma unroll
  for (int j = 1; j < 5; ++j)
    if (bid >= ds.d[j].off) i = j;
  const float* __restrict__ in = ds.d[i].src;
  bf16_t* __restrict__ out = ds.d[i].dst;
  const int K = ds.d[i].K, Nsrc = ds.d[i].Nsrc;
  const int local = bid - ds.d[i].off;
  const int n0 = (local % ds.d[i].bxc) * 32;
  const int k0 = (local / ds.d[i].bxc) * 32;
  int srcn0 = n0;
  if (ds.d[i].perm) {
    srcn0 = (n0 < 1024) ? ((n0 >> 6) * 192 + (n0 & 63))
                        : (((n0 - 1024) >> 7) * 192 + 64 + ((n0 - 1024) & 127));
  }
  int tx = threadIdx.x & 31, ty = threadIdx.x >> 5;
#pragma unroll
  for (int r = 0; r < 4; ++r) {
    int k = k0 + ty + r * 8, n = srcn0 + tx;
    tile[ty + r * 8][tx] = (n < Nsrc) ? in[(size_t)k * Nsrc + n] : 0.0f;
  }
  __syncthreads();
#pragma unroll
  for (int r = 0; r < 4; ++r) {
    int n = n0 + ty + r * 8, k = k0 + tx;
    out[(size_t)n * K + k] = (bf16_t)tile[tx][ty + r * 8];
  }
}

// ---------------- GEMM loop: 128x128 tile, BK=64, chunk-XOR swizzle, 2-phase dbuf ----------------
// LDS[row][chunk] holds global[row][chunk ^ (row&7)]; staged via pre-swizzled global source.
// Pipeline: STAGE(t+1) issued BEFORE compute(t); counted s_waitcnt vmcnt(8) waits only for
// tile-t's 8 loads (issued one iteration earlier -> latency hidden under compute(t-1)).
// Raw s_barrier (NOT __syncthreads) so the compiler can't inject a vmcnt(0) drain.

__device__ __forceinline__ void gemm_loop64(const bf16_t* __restrict__ A, int lda,
                                            const bf16_t* __restrict__ Bt, int K, int m0, int n0,
                                            int tid, bf16_t* Al, bf16_t* Bl, f32x4 (&acc)[4][4]) {
  const int wid = tid >> 6, lane = tid & 63;
  const int wm = (wid >> 1) * 64, wn = (wid & 1) * 64;
  const int srow8 = lane >> 3, c8 = lane & 7;
  const int swz8 = c8 ^ srow8;
  const int lr = lane & 15, lg = lane >> 4;
  const int e = lr & 7;

  const bf16_t* ag = A + (size_t)(m0 + wid * 32 + srow8) * lda + (swz8 << 3);
  const bf16_t* bg = Bt + (size_t)(n0 + wid * 32 + srow8) * K + (swz8 << 3);

  auto STAGE = [&](int buf, int k0) {
    bf16_t* ab = Al + buf * (128 * 64);
    bf16_t* bb = Bl + buf * (128 * 64);
#pragma unroll
    for (int rr = 0; rr < 4; ++rr) {
      load_lds16(ag + (size_t)(rr * 8) * lda + k0, &ab[(wid * 32 + rr * 8) * 64]);
      load_lds16(bg + (size_t)(rr * 8) * K + k0, &bb[(wid * 32 + rr * 8) * 64]);
    }
  };

  STAGE(0, 0);
  int cur = 0;
  for (int k0 = 0; k0 < K; k0 += 64) {
    if (k0 + 64 < K) {
      STAGE(cur ^ 1, k0 + 64);  // 8 new vmem ops into the other buffer
      __builtin_amdgcn_sched_barrier(0);
      asm volatile("s_waitcnt vmcnt(8)" ::: "memory");  // wait only for tile-t's 8
    } else {
      asm volatile("s_waitcnt vmcnt(0)" ::: "memory");  // last tile: full drain
    }
    __builtin_amdgcn_sched_barrier(0);
    __builtin_amdgcn_s_barrier();  // all waves' tile-t loads landed
    __builtin_amdgcn_sched_barrier(0);
    const bf16_t* Ab = Al + cur * (128 * 64);
    const bf16_t* Bb = Bl + cur * (128 * 64);
#pragma unroll
    for (int kk = 0; kk < 2; ++kk) {
      bf16x8 af[4], bfr[4];
#pragma unroll
      for (int i = 0; i < 4; ++i) {
        af[i] = load8(&Ab[(wm + i * 16 + lr) * 64 + (((kk * 4 + lg) ^ e) << 3)]);
        bfr[i] = load8(&Bb[(wn + i * 16 + lr) * 64 + (((kk * 4 + lg) ^ e) << 3)]);
      }
#pragma unroll
      for (int i = 0; i < 4; ++i)
#pragma unroll
        for (int j = 0; j < 4; ++j) acc[i][j] = mfma16x16(af[i], bfr[j], acc[i][j]);
    }
    __builtin_amdgcn_sched_barrier(0);
    __builtin_amdgcn_s_barrier();  // all waves done reading buf cur (reads retired via lgkmcnt)
    cur ^= 1;
  }
}

// ---------------- lat GEMM: lat = hsb @ [Wqa | Wkva(pad)] + fused k_pe RoPE ----------------
// 544 blocks (XCD-swizzled). C: [4096][2176]; cols 2048..2111 get RoPE.

__global__ __launch_bounds__(256) void gemm_lat_k(const bf16_t* __restrict__ A,
                                                  const bf16_t* __restrict__ Bt,
                                                  bf16_t* __restrict__ C,
                                                  const float* __restrict__ cosT,
                                                  const float* __restrict__ sinT) {
  __shared__ alignas(16) bf16_t Al[2 * 128 * 64];
  __shared__ alignas(16) bf16_t Bl[2 * 128 * 64];
  const int tid = threadIdx.x;
  const int sw = (blockIdx.x & 7) * 68 + (blockIdx.x >> 3);  // 544 = 8*68
  const int m0 = (sw / 17) * 128, n0 = (sw % 17) * 128;
  f32x4 acc[4][4] = {};
  gemm_loop64(A, 2048, Bt, 2048, m0, n0, tid, Al, Bl, acc);

  const int wid = tid >> 6, lane = tid & 63;
  const int wm = (wid >> 1) * 64, wn = (wid & 1) * 64;
  const int lr = lane & 15, lg = lane >> 4;
  const bool rope = (n0 == 2048) && (wn == 0);
  const int ir_base = lr >> 1;  // with j: ir = (j*16+lr)>>1 = j*8 + (lr>>1)
  const bool odd = lane & 1;
#pragma unroll
  for (int i = 0; i < 4; ++i)
#pragma unroll
    for (int j = 0; j < 4; ++j) {
      float v4[4];
#pragma unroll
      for (int r = 0; r < 4; ++r) v4[r] = acc[i][j][r];
      if (rope) {
        const int ir = j * 8 + ir_base;
#pragma unroll
        for (int r = 0; r < 4; ++r) {
          const int srow_ = (m0 + wm + i * 16 + lg * 4 + r) & (S_ - 1);
          float c = cosT[srow_ * 32 + ir], sn = sinT[srow_ * 32 + ir];
          float partner = __shfl_xor(v4[r], 1);
          v4[r] = odd ? (v4[r] * c + partner * sn) : (v4[r] * c - partner * sn);
        }
      }
#pragma unroll
      for (int r = 0; r < 4; ++r) {
        int row = m0 + wm + i * 16 + lg * 4 + r;
        int col = n0 + wn + j * 16 + lr;
        C[(size_t)row * 2176 + col] = (bf16_t)v4[r];
      }
    }
}

// ---------------- fused q-GEMM + kv-GEMM (one dispatch, 1280 blocks XCD-swizzled) ----------------
// role interleaved: q when sw%5<2 (512 q-blocks, 24 K-steps) else kv (768 blocks, 8 K-steps)
// -> uniform work mix across XCDs/time.
// q:  lat[:, :1536] @ Wqbt, scaled, fused q RoPE (wn==64 waves) -> qb [4096][2048]
// kv: lat[:, 1536:] @ Wkvbt(permuted): n0<1024 -> knb (k_nope); else vT (v transposed)

__global__ __launch_bounds__(256) void gemm_qkv_k(const bf16_t* __restrict__ lat,
                                                  const bf16_t* __restrict__ Wqbt,
                                                  const bf16_t* __restrict__ Wkvbt,
                                                  bf16_t* __restrict__ qb,
                                                  bf16_t* __restrict__ knb,
                                                  bf16_t* __restrict__ vT,
                                                  const float* __restrict__ cosT,
                                                  const float* __restrict__ sinT, float qscale) {
  __shared__ alignas(16) bf16_t Al[2 * 128 * 64];
  __shared__ alignas(16) bf16_t Bl[2 * 128 * 64];
  const int tid = threadIdx.x;
  const int sw = (blockIdx.x & 7) * 160 + (blockIdx.x >> 3);  // 1280 = 8*160
  const int wid = tid >> 6, lane = tid & 63;
  const int wm = (wid >> 1) * 64, wn = (wid & 1) * 64;
  const int lr = lane & 15, lg = lane >> 4;
  f32x4 acc[4][4] = {};
  const int r5 = sw % 5, q5 = sw / 5;

  if (r5 < 2) {
    const int qi = q5 * 2 + r5;  // 0..511
    const int m0 = (qi >> 4) * 128, n0 = (qi & 15) * 128;
    gemm_loop64(lat, 2176, Wqbt, 1536, m0, n0, tid, Al, Bl, acc);
    const bool rope = (wn == 64);  // d = wn + j*16 + lr; rope iff d >= 64
    const int ir_base = lr >> 1;
    const bool odd = lane & 1;
#pragma unroll
    for (int i = 0; i < 4; ++i)
#pragma unroll
      for (int j = 0; j < 4; ++j) {
        float v4[4];
#pragma unroll
        for (int r = 0; r < 4; ++r) v4[r] = acc[i][j][r] * qscale;
        if (rope) {
          const int ir = j * 8 + ir_base;
#pragma unroll
          for (int r = 0; r < 4; ++r) {
            const int srow_ = (m0 + wm + i * 16 + lg * 4 + r) & (S_ - 1);
            float c = cosT[srow_ * 32 + ir], sn = sinT[srow_ * 32 + ir];
            float partner = __shfl_xor(v4[r], 1);
            v4[r] = odd ? (v4[r] * c + partner * sn) : (v4[r] * c - partner * sn);
          }
        }
#pragma unroll
        for (int r = 0; r < 4; ++r) {
          int row = m0 + wm + i * 16 + lg * 4 + r;
          int col = n0 + wn + j * 16 + lr;
          qb[(size_t)row * 2048 + col] = (bf16_t)v4[r];
        }
      }
  } else {
    const int ki = q5 * 3 + (r5 - 2);  // 0..767
    const int m0 = (ki / 24) * 128, n0 = (ki % 24) * 128;
    gemm_loop64(lat + 1536, 2176, Wkvbt, 512, m0, n0, tid, Al, Bl, acc);
    if (n0 < 1024) {  // k_nope -> knb
#pragma unroll
      for (int i = 0; i < 4; ++i)
#pragma unroll
        for (int j = 0; j < 4; ++j)
#pragma unroll
          for (int r = 0; r < 4; ++r) {
            int row = m0 + wm + i * 16 + lg * 4 + r;
            int col = n0 + wn + j * 16 + lr;
            knb[(size_t)row * 1024 + col] = (bf16_t)acc[i][j][r];
          }
    } else {  // v -> vT, 4 consecutive tokens packed per store
#pragma unroll
      for (int i = 0; i < 4; ++i) {
        const int row0 = m0 + wm + i * 16 + lg * 4;
        const int bb = row0 >> 11;       // batch
        const int s0 = row0 & (S_ - 1);  // seq pos (multiple of 4)
#pragma unroll
        for (int j = 0; j < 4; ++j) {
          const int idx = n0 + wn + j * 16 + lr - 1024;
          const int h = idx >> 7, d = idx & 127;
          bf16x4 pk;
#pragma unroll
          for (int r = 0; r < 4; ++r) pk[r] = (bf16_t)acc[i][j][r];
          *reinterpret_cast<bf16x4*>(&vT[((size_t)(bb * 16 + h) * 128 + d) * 2048 + s0]) = pk;
        }
      }
    }
  }
}

// ---------------- out GEMM: out = attn @ Wo (f32 output, 512 blocks XCD-swizzled) ----------------

__global__ __launch_bounds__(256) void gemm_out_k(const bf16_t* __restrict__ A,
                                                  const bf16_t* __restrict__ Bt,
                                                  float* __restrict__ C) {
  __shared__ alignas(16) bf16_t Al[2 * 128 * 64];
  __shared__ alignas(16) bf16_t Bl[2 * 128 * 64];
  const int tid = threadIdx.x;
  const int sw = (blockIdx.x & 7) * 64 + (blockIdx.x >> 3);  // 512 = 8*64
  const int m0 = (sw >> 4) * 128, n0 = (sw & 15) * 128;
  f32x4 acc[4][4] = {};
  gemm_loop64(A, 2048, Bt, 2048, m0, n0, tid, Al, Bl, acc);
  const int wid = tid >> 6, lane = tid & 63;
  const int wm = (wid >> 1) * 64, wn = (wid & 1) * 64;
  const int lr = lane & 15, lg = lane >> 4;
#pragma unroll
  for (int i = 0; i < 4; ++i)
#pragma unroll
    for (int j = 0; j < 4; ++j)
#pragma unroll
      for (int r = 0; r < 4; ++r) {
        int row = m0 + wm + i * 16 + lg * 4 + r;
        int col = n0 + wn + j * 16 + lr;
        C[(size_t)row * 2048 + col] = acc[i][j][r];
      }
}

// ---------------- fused causal flash attention (swapped-QK^T, KVBLK=128) ----------------
// q:   [4096][2048] bf16 (pre-scaled by log2e/sqrt(128), q_pe roped)  col = h*128 + d
// knb: [4096][1024] bf16  col = h*64 + c (k_nope)
// lat: [4096][2176] bf16  cols 2048..2111 = roped k_pe (shared across heads)
// vT:  [32][128][2048] bf16  (V transposed per (b,h))
// out: [4096][2048] bf16  col = h*128 + d
//
// 1024 blocks x 256 threads, QBLK=64 (16 q-rows/wave), snake qt order.
// QK^T as mfma(K, Q) -> S^T: lane (lr,lg) reg r = S[qrow=lr][key=kt*16+lg*4+r].
// KVBLK=128: two 64-key tiles per iteration -> one softmax pass + one barrier pair
// per 128 keys. Causal mask on the last chunk also covers the odd-tile tail
// (keys past the diagonal get -1e30 -> contribute 0).
__global__ __launch_bounds__(256) void attn_fused(const bf16_t* __restrict__ q,
                                                  const bf16_t* __restrict__ knb,
                                                  const bf16_t* __restrict__ lat,
                                                  const bf16_t* __restrict__ vT,
                                                  bf16_t* __restrict__ out) {
  __shared__ alignas(16) bf16_t Kn[128 * 64];
  __shared__ alignas(16) bf16_t Kp[128 * 64];
  __shared__ alignas(16) bf16_t Vt[128 * 128];
  __shared__ alignas(16) bf16_t Pl[4][16 * 128];
  const int tid = threadIdx.x, wid = tid >> 6, lane = tid & 63;
  const int bid = blockIdx.x;
  const int g = bid >> 8;        // band 0..3
  const int x = (bid >> 5) & 7;  // position within band
  const int bh = bid & 31;
  const int qt = (g & 1) ? (24 - g * 8 + x) : (31 - g * 8 - x);  // snake
  const int b = bh >> 4, h = bh & 15;
  const int tokb = b * S_;
  const int lr = lane & 15, lg = lane >> 4;
  const int e7 = lr & 7;
  const int srow8 = lane >> 3, c8 = lane & 7;
  const int swz8 = c8 ^ srow8;                    // 64-wide rows: 8 chunks
  const int srow16 = lane >> 4, c16 = lane & 15;  // 128-wide rows: 16 chunks
  bf16_t* Pw = &Pl[wid][0];

  bf16x8 ones;
#pragma unroll
  for (int j = 0; j < 8; ++j) ones[j] = (bf16_t)1.0f;

  bf16x8 qf[4];
  {
    const int qrow = qt * 64 + wid * 16 + lr;
    const bf16_t* qp = q + (size_t)(tokb + qrow) * 2048 + h * 128 + lg * 8;
#pragma unroll
    for (int ds = 0; ds < 4; ++ds) qf[ds] = load8(qp + ds * 32);
  }

  f32x4 o[8] = {};
  f32x4 o8 = {};     // row-sums of P (softmax denominator), via matrix pipe
  float m = -1e30f;  // running max of row qrow=lr (one per lane)
  const int qr_glob = qt * 64 + wid * 16 + lr;
  const int lastch = qt >> 1;

  for (int ch = 0; ch <= lastch; ++ch) {
    const int kb = ch * 128;
    // ---- stage Kn/Kp (128x64) + Vt (128x128), pre-swizzled source ----
#pragma unroll
    for (int rr = 0; rr < 4; ++rr) {
      const int r0 = wid * 32 + rr * 8;
      const size_t tk = (size_t)(tokb + kb + r0 + srow8);
      load_lds16(knb + tk * 1024 + h * 64 + (swz8 << 3), &Kn[r0 * 64]);
      load_lds16(lat + tk * 2176 + 2048 + (swz8 << 3), &Kp[r0 * 64]);
    }
#pragma unroll
    for (int rr = 0; rr < 8; ++rr) {
      const int r0 = wid * 32 + rr * 4;
      const int row = r0 + srow16;
      load_lds16(vT + ((size_t)bh * 128 + row) * 2048 + kb + ((c16 ^ (row & 7)) << 3),
                 &Vt[r0 * 128]);
    }
    __syncthreads();

    // ---- S^T = K Q^T : 8 key-sub-tiles of 16 ----
    f32x4 s[8];
    __builtin_amdgcn_s_setprio(1);
#pragma unroll
    for (int kt = 0; kt < 8; ++kt) {
      const int row = kt * 16 + lr;  // row&7 == lr&7 == e7
      bf16x8 kf0 = load8(&Kn[row * 64 + ((lg ^ e7) << 3)]);
      bf16x8 kf1 = load8(&Kn[row * 64 + (((lg + 4) ^ e7) << 3)]);
      bf16x8 kf2 = load8(&Kp[row * 64 + ((lg ^ e7) << 3)]);
      bf16x8 kf3 = load8(&Kp[row * 64 + (((lg + 4) ^ e7) << 3)]);
      f32x4 acc = {0.f, 0.f, 0.f, 0.f};
      acc = mfma16x16(kf0, qf[0], acc);  // swapped: A=K, B=Q -> S^T
      acc = mfma16x16(kf1, qf[1], acc);
      acc = mfma16x16(kf2, qf[2], acc);
      acc = mfma16x16(kf3, qf[3], acc);
      s[kt] = acc;
    }
    __builtin_amdgcn_s_setprio(0);

    if (ch == lastch) {  // causal mask (also covers odd-tile tail past diagonal)
#pragma unroll
      for (int kt = 0; kt < 8; ++kt)
#pragma unroll
        for (int r = 0; r < 4; ++r) {
          const int key = kb + kt * 16 + lg * 4 + r;
          if (key > qr_glob) s[kt][r] = -1e30f;
        }
    }

    // ---- online softmax (exp2 domain, defer-max THR=8), one pass per 128 keys ----
    float tm;
    {
      float a0 = fmaxf(fmaxf(s[0][0], s[0][1]), fmaxf(s[0][2], s[0][3]));
      float a1 = fmaxf(fmaxf(s[1][0], s[1][1]), fmaxf(s[1][2], s[1][3]));
      float a2 = fmaxf(fmaxf(s[2][0], s[2][1]), fmaxf(s[2][2], s[2][3]));
      float a3 = fmaxf(fmaxf(s[3][0], s[3][1]), fmaxf(s[3][2], s[3][3]));
      float a4 = fmaxf(fmaxf(s[4][0], s[4][1]), fmaxf(s[4][2], s[4][3]));
      float a5 = fmaxf(fmaxf(s[5][0], s[5][1]), fmaxf(s[5][2], s[5][3]));
      float a6 = fmaxf(fmaxf(s[6][0], s[6][1]), fmaxf(s[6][2], s[6][3]));
      float a7 = fmaxf(fmaxf(s[7][0], s[7][1]), fmaxf(s[7][2], s[7][3]));
      tm = fmaxf(fmaxf(fmaxf(a0, a1), fmaxf(a2, a3)), fmaxf(fmaxf(a4, a5), fmaxf(a6, a7)));
      tm = fmaxf(tm, __shfl_xor(tm, 16));
      tm = fmaxf(tm, __shfl_xor(tm, 32));
    }
    if (!__all(tm - m <= 8.0f)) {
      float mn = fmaxf(m, tm);
      float corr = exp2f(m - mn);
      m = mn;
      float corrv[4];
#pragma unroll
      for (int r = 0; r < 4; ++r) corrv[r] = __shfl(corr, lg * 4 + r);
#pragma unroll
      for (int r = 0; r < 4; ++r) {
        o8[r] *= corrv[r];
#pragma unroll
        for (int n = 0; n < 8; ++n) o[n][r] *= corrv[r];
      }
    }
#pragma unroll
    for (int kt = 0; kt < 8; ++kt)
#pragma unroll
      for (int r = 0; r < 4; ++r) s[kt][r] = exp2f(s[kt][r] - m);

    // ---- stage P [16][128]: 4 consecutive keys per reg group -> bf16x4 b64 (swizzled) ----
#pragma unroll
    for (int kt = 0; kt < 8; ++kt) {
      bf16x4 pk;
#pragma unroll
      for (int r = 0; r < 4; ++r) pk[r] = (bf16_t)s[kt][r];
      const int c = kt * 2 + (lg >> 1);  // 8-elem chunk index of key group (0..15)
      *reinterpret_cast<bf16x4*>(&Pw[lr * 128 + ((c ^ e7) << 3) + ((lg & 1) << 2)]) = pk;
    }

    // ---- O += P @ V ; l += P @ ones (4 key-steps of 32) ----
    __builtin_amdgcn_s_setprio(1);
#pragma unroll
    for (int ks = 0; ks < 4; ++ks) {
      bf16x8 pa = load8(&Pw[lr * 128 + (((ks * 4 + lg) ^ e7) << 3)]);
#pragma unroll
      for (int n = 0; n < 8; ++n) {
        bf16x8 vb = load8(&Vt[(n * 16 + lr) * 128 + (((ks * 4 + lg) ^ e7) << 3)]);
        o[n] = mfma16x16(pa, vb, o[n]);
      }
      o8 = mfma16x16(pa, ones, o8);
    }
    __builtin_amdgcn_s_setprio(0);
    __syncthreads();
  }

  float linv[4];
#pragma unroll
  for (int r = 0; r < 4; ++r) linv[r] = __builtin_amdgcn_rcpf(o8[r]);
#pragma unroll
  for (int n = 0; n < 8; ++n)
#pragma unroll
    for (int r = 0; r < 4; ++r) {
      const int qr = qt * 64 + wid * 16 + lg * 4 + r;
      out[(size_t)(tokb + qr) * 2048 + h * 128 + n * 16 + lr] = (bf16_t)(o[n][r] * linv[r]);
    }
}

// ---------------- launch ----------------

extern "C" void kernel_launch(void* const* d_in, const int* in_sizes, int n_in, void* d_out,
                              int out_size, void* d_ws, size_t ws_size, hipStream_t stream) {
  const float* hs = (const float*)d_in[0];
  const float* Wqa = (const float*)d_in[1];
  const float* Wqb = (const float*)d_in[2];
  const float* Wkva = (const float*)d_in[3];
  const float* Wkvb = (const float*)d_in[4];
  const float* Wo = (const float*)d_in[5];
  float* out = (float*)d_out;

  char* ws = (char*)d_ws;
  size_t off = 0;
  auto alloc = [&](size_t bytes) {
    void* p = ws + off;
    off += (bytes + 255) & ~(size_t)255;
    return p;
  };
  bf16_t* hsb = (bf16_t*)alloc((size_t)NTOK * 2048 * 2);
  bf16_t* W1t = (bf16_t*)alloc((size_t)2176 * 2048 * 2);
  bf16_t* Wqbt = (bf16_t*)alloc((size_t)2048 * 1536 * 2);
  bf16_t* Wkvbt = (bf16_t*)alloc((size_t)3072 * 512 * 2);
  bf16_t* Wot = (bf16_t*)alloc((size_t)2048 * 2048 * 2);
  bf16_t* lat = (bf16_t*)alloc((size_t)NTOK * 2176 * 2);
  bf16_t* qb = (bf16_t*)alloc((size_t)NTOK * 2048 * 2);
  bf16_t* knb = (bf16_t*)alloc((size_t)NTOK * 1024 * 2);
  bf16_t* attn = (bf16_t*)alloc((size_t)NTOK * 2048 * 2);
  bf16_t* vT = (bf16_t*)alloc((size_t)32 * 128 * 2048 * 2);
  float* cosT = (float*)alloc((size_t)S_ * 32 * 4);
  float* sinT = (float*)alloc((size_t)S_ * 32 * 4);

  // prep
  cast_bf16_k<<<(NTOK * 2048 / 4 + 255) / 256, 256, 0, stream>>>(hs, hsb, NTOK * 2048);
  rope_tables_k<<<(S_ * 32 + 255) / 256, 256, 0, stream>>>(cosT, sinT);
  {
    TDesc5 ds;
    int o0 = 0;
    auto add = [&](int i, const float* src, bf16_t* dst, int K, int Nsrc, int Nout, int perm) {
      int bxc = Nout / 32, cnt = bxc * (K / 32);
      ds.d[i] = TDesc{src, dst, K, Nsrc, bxc, o0, perm};
      o0 += cnt;
    };
    add(0, Wqa, W1t, 2048, 1536, 1536, 0);
    add(1, Wkva, W1t + (size_t)1536 * 2048, 2048, 576, 640, 0);
    add(2, Wqb, Wqbt, 1536, 2048, 2048, 0);
    add(3, Wkvb, Wkvbt, 512, 3072, 3072, 1);
    add(4, Wo, Wot, 2048, 2048, 2048, 0);
    transpose_cast_multi_k<<<o0, 256, 0, stream>>>(ds);
  }

  // lat = hsb @ [Wqa | Wkva(pad to 640)]  + fused k_pe RoPE
  gemm_lat_k<<<dim3(544), 256, 0, stream>>>(hsb, W1t, lat, cosT, sinT);
  // q (+RoPE, scaled) and kv (knb + vT) in one dispatch (role-interleaved)
  const float scale = 0.08838834764831845f * 1.4426950408889634f;  // 1/sqrt(128)*log2e
  gemm_qkv_k<<<dim3(1280), 256, 0, stream>>>(lat, Wqbt, Wkvbt, qb, knb, vT, cosT, sinT, scale);
  // attention (16x16 swapped-QK^T, KVBLK=128)
  attn_fused<<<dim3(1024), 256, 0, stream>>>(qb, knb, lat, vT, attn);
  // out = attn @ Wo (f32 output)
  gemm_out_k<<<dim3(512), 256, 0, stream>>>(attn, Wot, out);
}

// Round 15
// 271.044 us; speedup vs baseline: 1.1541x; 1.1541x over previous
//
#include <hip/hip_runtime.h>
#include <hip/hip_bf16.h>
#include <cstdint>
#include <cstddef>

typedef __bf16 bf16_t;
typedef __attribute__((ext_vector_type(4))) __bf16 bf16x4;
typedef __attribute__((ext_vector_type(8))) __bf16 bf16x8;
typedef __attribute__((ext_vector_type(4))) float f32x4;

#define S_ 2048
#define H_ 16
#define NTOK 4096

__device__ __forceinline__ f32x4 mfma16x16(bf16x8 a, bf16x8 b, f32x4 c) {
  return __builtin_amdgcn_mfma_f32_16x16x32_bf16(a, b, c, 0, 0, 0);
}
__device__ __forceinline__ bf16x8 load8(const bf16_t* p) {
  return *reinterpret_cast<const bf16x8*>(p);
}
__device__ __forceinline__ void load_lds16(const void* g, void* l) {
  __builtin_amdgcn_global_load_lds(
      (const __attribute__((address_space(1))) uint32_t*)g,
      (__attribute__((address_space(3))) uint32_t*)l, 16, 0, 0);
}

// ---------------- merged prep kernel: cast | rope tables | 5x transpose ----------------
// Block-role dispatch: [0, castB) elementwise f32->bf16 cast of hidden_states;
// [castB, castB+ropeB) rope cos/sin tables; rest: weight transpose+cast jobs.
// perm==1 (Wkvb job): output row n maps to src col f(n) so the kv GEMM's N axis
// becomes [16*64 k_nope | 16*128 v]; per 32-col block the src stays contiguous.

struct TDesc {
  const float* src;
  bf16_t* dst;
  int K, Nsrc, bxc, off, perm;
};
struct TDesc5 {
  TDesc d[5];
};

__global__ void prep_all_k(const float* __restrict__ hs, bf16_t* __restrict__ hsb, int ncast,
                           float* __restrict__ cosT, float* __restrict__ sinT, TDesc5 ds,
                           int castB, int ropeB) {
  __shared__ float tile[32][33];
  int bid = blockIdx.x;

  if (bid < castB) {  // ---- cast hidden_states to bf16 ----
    int idx = bid * 256 + threadIdx.x;
    int i4 = idx * 4;
    if (i4 < ncast) {
      float4 v = *reinterpret_cast<const float4*>(hs + i4);
      hsb[i4 + 0] = (bf16_t)v.x;
      hsb[i4 + 1] = (bf16_t)v.y;
      hsb[i4 + 2] = (bf16_t)v.z;
      hsb[i4 + 3] = (bf16_t)v.w;
    }
    return;
  }
  bid -= castB;

  if (bid < ropeB) {  // ---- rope cos/sin tables ----
    int idx = bid * 256 + threadIdx.x;
    if (idx < S_ * 32) {
      int s = idx >> 5, i = idx & 31;
      float inv = powf(10000.0f, -(2.0f * (float)i) / 64.0f);
      float fr = (float)s * inv;
      cosT[idx] = cosf(fr);
      sinT[idx] = sinf(fr);
    }
    return;
  }
  bid -= ropeB;

  // ---- weight transpose+cast ----
  int i = 0;
#pragma unroll
  for (int j = 1; j < 5; ++j)
    if (bid >= ds.d[j].off) i = j;
  const float* __restrict__ in = ds.d[i].src;
  bf16_t* __restrict__ out = ds.d[i].dst;
  const int K = ds.d[i].K, Nsrc = ds.d[i].Nsrc;
  const int local = bid - ds.d[i].off;
  const int n0 = (local % ds.d[i].bxc) * 32;
  const int k0 = (local / ds.d[i].bxc) * 32;
  int srcn0 = n0;
  if (ds.d[i].perm) {
    srcn0 = (n0 < 1024) ? ((n0 >> 6) * 192 + (n0 & 63))
                        : (((n0 - 1024) >> 7) * 192 + 64 + ((n0 - 1024) & 127));
  }
  int tx = threadIdx.x & 31, ty = threadIdx.x >> 5;
#pragma unroll
  for (int r = 0; r < 4; ++r) {
    int k = k0 + ty + r * 8, n = srcn0 + tx;
    tile[ty + r * 8][tx] = (n < Nsrc) ? in[(size_t)k * Nsrc + n] : 0.0f;
  }
  __syncthreads();
#pragma unroll
  for (int r = 0; r < 4; ++r) {
    int n = n0 + ty + r * 8, k = k0 + tx;
    out[(size_t)n * K + k] = (bf16_t)tile[tx][ty + r * 8];
  }
}

// ---------------- GEMM loop: 128x128 tile, BK=64, chunk-XOR swizzle, 2-phase dbuf ----------------
// LDS[row][chunk] holds global[row][chunk ^ (row&7)]; staged via pre-swizzled global source.
// Pipeline: STAGE(t+1) issued BEFORE compute(t); counted s_waitcnt vmcnt(8) waits only for
// tile-t's 8 loads (issued one iteration earlier -> latency hidden under compute(t-1)).
// Raw s_barrier (NOT __syncthreads) so the compiler can't inject a vmcnt(0) drain.

__device__ __forceinline__ void gemm_loop64(const bf16_t* __restrict__ A, int lda,
                                            const bf16_t* __restrict__ Bt, int K, int m0, int n0,
                                            int tid, bf16_t* Al, bf16_t* Bl, f32x4 (&acc)[4][4]) {
  const int wid = tid >> 6, lane = tid & 63;
  const int wm = (wid >> 1) * 64, wn = (wid & 1) * 64;
  const int srow8 = lane >> 3, c8 = lane & 7;
  const int swz8 = c8 ^ srow8;
  const int lr = lane & 15, lg = lane >> 4;
  const int e = lr & 7;

  const bf16_t* ag = A + (size_t)(m0 + wid * 32 + srow8) * lda + (swz8 << 3);
  const bf16_t* bg = Bt + (size_t)(n0 + wid * 32 + srow8) * K + (swz8 << 3);

  auto STAGE = [&](int buf, int k0) {
    bf16_t* ab = Al + buf * (128 * 64);
    bf16_t* bb = Bl + buf * (128 * 64);
#pragma unroll
    for (int rr = 0; rr < 4; ++rr) {
      load_lds16(ag + (size_t)(rr * 8) * lda + k0, &ab[(wid * 32 + rr * 8) * 64]);
      load_lds16(bg + (size_t)(rr * 8) * K + k0, &bb[(wid * 32 + rr * 8) * 64]);
    }
  };

  STAGE(0, 0);
  int cur = 0;
  for (int k0 = 0; k0 < K; k0 += 64) {
    if (k0 + 64 < K) {
      STAGE(cur ^ 1, k0 + 64);  // 8 new vmem ops into the other buffer
      __builtin_amdgcn_sched_barrier(0);
      asm volatile("s_waitcnt vmcnt(8)" ::: "memory");  // wait only for tile-t's 8
    } else {
      asm volatile("s_waitcnt vmcnt(0)" ::: "memory");  // last tile: full drain
    }
    __builtin_amdgcn_sched_barrier(0);
    __builtin_amdgcn_s_barrier();  // all waves' tile-t loads landed
    __builtin_amdgcn_sched_barrier(0);
    const bf16_t* Ab = Al + cur * (128 * 64);
    const bf16_t* Bb = Bl + cur * (128 * 64);
#pragma unroll
    for (int kk = 0; kk < 2; ++kk) {
      bf16x8 af[4], bfr[4];
#pragma unroll
      for (int i = 0; i < 4; ++i) {
        af[i] = load8(&Ab[(wm + i * 16 + lr) * 64 + (((kk * 4 + lg) ^ e) << 3)]);
        bfr[i] = load8(&Bb[(wn + i * 16 + lr) * 64 + (((kk * 4 + lg) ^ e) << 3)]);
      }
#pragma unroll
      for (int i = 0; i < 4; ++i)
#pragma unroll
        for (int j = 0; j < 4; ++j) acc[i][j] = mfma16x16(af[i], bfr[j], acc[i][j]);
    }
    __builtin_amdgcn_sched_barrier(0);
    __builtin_amdgcn_s_barrier();  // all waves done reading buf cur (reads retired via lgkmcnt)
    cur ^= 1;
  }
}

// ---------------- lat GEMM: lat = hsb @ [Wqa | Wkva(pad)] + fused k_pe RoPE ----------------
// 544 blocks (XCD-swizzled). C: [4096][2176]; cols 2048..2111 get RoPE.

__global__ __launch_bounds__(256) void gemm_lat_k(const bf16_t* __restrict__ A,
                                                  const bf16_t* __restrict__ Bt,
                                                  bf16_t* __restrict__ C,
                                                  const float* __restrict__ cosT,
                                                  const float* __restrict__ sinT) {
  __shared__ alignas(16) bf16_t Al[2 * 128 * 64];
  __shared__ alignas(16) bf16_t Bl[2 * 128 * 64];
  const int tid = threadIdx.x;
  const int sw = (blockIdx.x & 7) * 68 + (blockIdx.x >> 3);  // 544 = 8*68
  const int m0 = (sw / 17) * 128, n0 = (sw % 17) * 128;
  f32x4 acc[4][4] = {};
  gemm_loop64(A, 2048, Bt, 2048, m0, n0, tid, Al, Bl, acc);

  const int wid = tid >> 6, lane = tid & 63;
  const int wm = (wid >> 1) * 64, wn = (wid & 1) * 64;
  const int lr = lane & 15, lg = lane >> 4;
  const bool rope = (n0 == 2048) && (wn == 0);
  const int ir_base = lr >> 1;  // with j: ir = (j*16+lr)>>1 = j*8 + (lr>>1)
  const bool odd = lane & 1;
#pragma unroll
  for (int i = 0; i < 4; ++i)
#pragma unroll
    for (int j = 0; j < 4; ++j) {
      float v4[4];
#pragma unroll
      for (int r = 0; r < 4; ++r) v4[r] = acc[i][j][r];
      if (rope) {
        const int ir = j * 8 + ir_base;
#pragma unroll
        for (int r = 0; r < 4; ++r) {
          const int srow_ = (m0 + wm + i * 16 + lg * 4 + r) & (S_ - 1);
          float c = cosT[srow_ * 32 + ir], sn = sinT[srow_ * 32 + ir];
          float partner = __shfl_xor(v4[r], 1);
          v4[r] = odd ? (v4[r] * c + partner * sn) : (v4[r] * c - partner * sn);
        }
      }
#pragma unroll
      for (int r = 0; r < 4; ++r) {
        int row = m0 + wm + i * 16 + lg * 4 + r;
        int col = n0 + wn + j * 16 + lr;
        C[(size_t)row * 2176 + col] = (bf16_t)v4[r];
      }
    }
}

// ---------------- fused q-GEMM + kv-GEMM (one dispatch, 1280 blocks XCD-swizzled) ----------------
// role interleaved: q when sw%5<2 (512 q-blocks, 24 K-steps) else kv (768 blocks, 8 K-steps).
// q:  lat[:, :1536] @ Wqbt, scaled, fused q RoPE (wn==64 waves) -> qb [4096][2048]
// kv: lat[:, 1536:] @ Wkvbt(permuted): n0<1024 -> knb (k_nope); else vT (v transposed)

__global__ __launch_bounds__(256) void gemm_qkv_k(const bf16_t* __restrict__ lat,
                                                  const bf16_t* __restrict__ Wqbt,
                                                  const bf16_t* __restrict__ Wkvbt,
                                                  bf16_t* __restrict__ qb,
                                                  bf16_t* __restrict__ knb,
                                                  bf16_t* __restrict__ vT,
                                                  const float* __restrict__ cosT,
                                                  const float* __restrict__ sinT, float qscale) {
  __shared__ alignas(16) bf16_t Al[2 * 128 * 64];
  __shared__ alignas(16) bf16_t Bl[2 * 128 * 64];
  const int tid = threadIdx.x;
  const int sw = (blockIdx.x & 7) * 160 + (blockIdx.x >> 3);  // 1280 = 8*160
  const int wid = tid >> 6, lane = tid & 63;
  const int wm = (wid >> 1) * 64, wn = (wid & 1) * 64;
  const int lr = lane & 15, lg = lane >> 4;
  f32x4 acc[4][4] = {};
  const int r5 = sw % 5, q5 = sw / 5;

  if (r5 < 2) {
    const int qi = q5 * 2 + r5;  // 0..511
    const int m0 = (qi >> 4) * 128, n0 = (qi & 15) * 128;
    gemm_loop64(lat, 2176, Wqbt, 1536, m0, n0, tid, Al, Bl, acc);
    const bool rope = (wn == 64);  // d = wn + j*16 + lr; rope iff d >= 64
    const int ir_base = lr >> 1;
    const bool odd = lane & 1;
#pragma unroll
    for (int i = 0; i < 4; ++i)
#pragma unroll
      for (int j = 0; j < 4; ++j) {
        float v4[4];
#pragma unroll
        for (int r = 0; r < 4; ++r) v4[r] = acc[i][j][r] * qscale;
        if (rope) {
          const int ir = j * 8 + ir_base;
#pragma unroll
          for (int r = 0; r < 4; ++r) {
            const int srow_ = (m0 + wm + i * 16 + lg * 4 + r) & (S_ - 1);
            float c = cosT[srow_ * 32 + ir], sn = sinT[srow_ * 32 + ir];
            float partner = __shfl_xor(v4[r], 1);
            v4[r] = odd ? (v4[r] * c + partner * sn) : (v4[r] * c - partner * sn);
          }
        }
#pragma unroll
        for (int r = 0; r < 4; ++r) {
          int row = m0 + wm + i * 16 + lg * 4 + r;
          int col = n0 + wn + j * 16 + lr;
          qb[(size_t)row * 2048 + col] = (bf16_t)v4[r];
        }
      }
  } else {
    const int ki = q5 * 3 + (r5 - 2);  // 0..767
    const int m0 = (ki / 24) * 128, n0 = (ki % 24) * 128;
    gemm_loop64(lat + 1536, 2176, Wkvbt, 512, m0, n0, tid, Al, Bl, acc);
    if (n0 < 1024) {  // k_nope -> knb
#pragma unroll
      for (int i = 0; i < 4; ++i)
#pragma unroll
        for (int j = 0; j < 4; ++j)
#pragma unroll
          for (int r = 0; r < 4; ++r) {
            int row = m0 + wm + i * 16 + lg * 4 + r;
            int col = n0 + wn + j * 16 + lr;
            knb[(size_t)row * 1024 + col] = (bf16_t)acc[i][j][r];
          }
    } else {  // v -> vT, 4 consecutive tokens packed per store
#pragma unroll
      for (int i = 0; i < 4; ++i) {
        const int row0 = m0 + wm + i * 16 + lg * 4;
        const int bb = row0 >> 11;       // batch
        const int s0 = row0 & (S_ - 1);  // seq pos (multiple of 4)
#pragma unroll
        for (int j = 0; j < 4; ++j) {
          const int idx = n0 + wn + j * 16 + lr - 1024;
          const int h = idx >> 7, d = idx & 127;
          bf16x4 pk;
#pragma unroll
          for (int r = 0; r < 4; ++r) pk[r] = (bf16_t)acc[i][j][r];
          *reinterpret_cast<bf16x4*>(&vT[((size_t)(bb * 16 + h) * 128 + d) * 2048 + s0]) = pk;
        }
      }
    }
  }
}

// ---------------- out GEMM: out = attn @ Wo (f32 output, 512 blocks XCD-swizzled) ----------------

__global__ __launch_bounds__(256) void gemm_out_k(const bf16_t* __restrict__ A,
                                                  const bf16_t* __restrict__ Bt,
                                                  float* __restrict__ C) {
  __shared__ alignas(16) bf16_t Al[2 * 128 * 64];
  __shared__ alignas(16) bf16_t Bl[2 * 128 * 64];
  const int tid = threadIdx.x;
  const int sw = (blockIdx.x & 7) * 64 + (blockIdx.x >> 3);  // 512 = 8*64
  const int m0 = (sw >> 4) * 128, n0 = (sw & 15) * 128;
  f32x4 acc[4][4] = {};
  gemm_loop64(A, 2048, Bt, 2048, m0, n0, tid, Al, Bl, acc);
  const int wid = tid >> 6, lane = tid & 63;
  const int wm = (wid >> 1) * 64, wn = (wid & 1) * 64;
  const int lr = lane & 15, lg = lane >> 4;
#pragma unroll
  for (int i = 0; i < 4; ++i)
#pragma unroll
    for (int j = 0; j < 4; ++j)
#pragma unroll
      for (int r = 0; r < 4; ++r) {
        int row = m0 + wm + i * 16 + lg * 4 + r;
        int col = n0 + wn + j * 16 + lr;
        C[(size_t)row * 2048 + col] = acc[i][j][r];
      }
}

// ---------------- fused causal flash attention (swapped-QK^T softmax, R9 config) ----------------
// q:   [4096][2048] bf16 (pre-scaled by log2e/sqrt(128), q_pe roped)  col = h*128 + d
// knb: [4096][1024] bf16  col = h*64 + c (k_nope)
// lat: [4096][2176] bf16  cols 2048..2111 = roped k_pe (shared across heads)
// vT:  [32][128][2048] bf16  (V transposed per (b,h))
// out: [4096][2048] bf16  col = h*128 + d
//
// QK^T computed as mfma(K, Q) -> S^T tile: lane (lr,lg) reg r = S[qrow=lr][key=kt*16+lg*4+r].
// One q-row per lane -> row-max = 15 fmax + 2 shfl; P staged as 4x bf16x4 b64 writes.
__global__ __launch_bounds__(256) void attn_fused(const bf16_t* __restrict__ q,
                                                  const bf16_t* __restrict__ knb,
                                                  const bf16_t* __restrict__ lat,
                                                  const bf16_t* __restrict__ vT,
                                                  bf16_t* __restrict__ out) {
  __shared__ alignas(16) bf16_t Kn[64 * 64];
  __shared__ alignas(16) bf16_t Kp[64 * 64];
  __shared__ alignas(16) bf16_t Vt[128 * 64];
  __shared__ alignas(16) bf16_t Pl[4][16 * 64];
  const int tid = threadIdx.x, wid = tid >> 6, lane = tid & 63;
  const int bid = blockIdx.x;
  const int g = bid >> 8;        // band 0..3
  const int x = (bid >> 5) & 7;  // position within band
  const int bh = bid & 31;
  const int qt = (g & 1) ? (24 - g * 8 + x) : (31 - g * 8 - x);  // snake
  const int b = bh >> 4, h = bh & 15;
  const int tokb = b * S_;
  const int lr = lane & 15, lg = lane >> 4;
  const int srow8 = lane >> 3, c8 = lane & 7;
  const int swz8 = c8 ^ srow8;  // swizzled chunk for staging source
  bf16_t* Pw = &Pl[wid][0];

  bf16x8 ones;
#pragma unroll
  for (int j = 0; j < 8; ++j) ones[j] = (bf16_t)1.0f;

  bf16x8 qf[4];
  {
    const int qrow = qt * 64 + wid * 16 + lr;
    const bf16_t* qp = q + (size_t)(tokb + qrow) * 2048 + h * 128 + lg * 8;
#pragma unroll
    for (int ds = 0; ds < 4; ++ds) qf[ds] = load8(qp + ds * 32);
  }

  f32x4 o[8] = {};
  f32x4 o8 = {};     // row-sums of P (softmax denominator), via matrix pipe
  float m = -1e30f;  // running max of row qrow=lr (one per lane)
  const int qr_glob = qt * 64 + wid * 16 + lr;

  for (int t = 0; t <= qt; ++t) {
    const int kb = t * 64;
#pragma unroll
    for (int rr = 0; rr < 2; ++rr) {
      const int r0 = wid * 16 + rr * 8;
      const size_t tk = (size_t)(tokb + kb + r0 + srow8);
      load_lds16(knb + tk * 1024 + h * 64 + (swz8 << 3), &Kn[r0 * 64]);
      load_lds16(lat + tk * 2176 + 2048 + (swz8 << 3), &Kp[r0 * 64]);
    }
#pragma unroll
    for (int rr = 0; rr < 4; ++rr) {
      const int r0 = wid * 32 + rr * 8;
      load_lds16(vT + ((size_t)bh * 128 + r0 + srow8) * 2048 + kb + (swz8 << 3), &Vt[r0 * 64]);
    }
    __syncthreads();

    // ---- S^T = K Q^T : lane (lr,lg) reg r = S[qrow=lr][key=kt*16+lg*4+r] ----
    f32x4 s[4];
    __builtin_amdgcn_s_setprio(1);
#pragma unroll
    for (int kt = 0; kt < 4; ++kt) {
      const int row = kt * 16 + lr;
      const int e = lr & 7;
      bf16x8 kf0 = load8(&Kn[row * 64 + ((lg ^ e) << 3)]);
      bf16x8 kf1 = load8(&Kn[row * 64 + (((lg + 4) ^ e) << 3)]);
      bf16x8 kf2 = load8(&Kp[row * 64 + ((lg ^ e) << 3)]);
      bf16x8 kf3 = load8(&Kp[row * 64 + (((lg + 4) ^ e) << 3)]);
      f32x4 acc = {0.f, 0.f, 0.f, 0.f};
      acc = mfma16x16(kf0, qf[0], acc);  // swapped: A=K, B=Q -> S^T
      acc = mfma16x16(kf1, qf[1], acc);
      acc = mfma16x16(kf2, qf[2], acc);
      acc = mfma16x16(kf3, qf[3], acc);
      s[kt] = acc;
    }
    __builtin_amdgcn_s_setprio(0);

    if (t == qt) {  // causal mask on diagonal tile
#pragma unroll
      for (int kt = 0; kt < 4; ++kt)
#pragma unroll
        for (int r = 0; r < 4; ++r) {
          const int key = kb + kt * 16 + lg * 4 + r;
          if (key > qr_glob) s[kt][r] = -1e30f;
        }
    }

    // ---- online softmax (exp2 domain, defer-max THR=8), per-lane row ----
    float tm;
    {
      float a0 = fmaxf(fmaxf(s[0][0], s[0][1]), fmaxf(s[0][2], s[0][3]));
      float a1 = fmaxf(fmaxf(s[1][0], s[1][1]), fmaxf(s[1][2], s[1][3]));
      float a2 = fmaxf(fmaxf(s[2][0], s[2][1]), fmaxf(s[2][2], s[2][3]));
      float a3 = fmaxf(fmaxf(s[3][0], s[3][1]), fmaxf(s[3][2], s[3][3]));
      tm = fmaxf(fmaxf(a0, a1), fmaxf(a2, a3));
      tm = fmaxf(tm, __shfl_xor(tm, 16));
      tm = fmaxf(tm, __shfl_xor(tm, 32));
    }
    if (!__all(tm - m <= 8.0f)) {
      float mn = fmaxf(m, tm);
      float corr = exp2f(m - mn);
      m = mn;
      float corrv[4];
#pragma unroll
      for (int r = 0; r < 4; ++r) corrv[r] = __shfl(corr, lg * 4 + r);
#pragma unroll
      for (int r = 0; r < 4; ++r) {
        o8[r] *= corrv[r];
#pragma unroll
        for (int n = 0; n < 8; ++n) o[n][r] *= corrv[r];
      }
    }
#pragma unroll
    for (int kt = 0; kt < 4; ++kt)
#pragma unroll
      for (int r = 0; r < 4; ++r) s[kt][r] = exp2f(s[kt][r] - m);

    // ---- stage P: 4 consecutive keys per reg group -> bf16x4 b64 writes (swizzled) ----
#pragma unroll
    for (int kt = 0; kt < 4; ++kt) {
      bf16x4 pk;
#pragma unroll
      for (int r = 0; r < 4; ++r) pk[r] = (bf16_t)s[kt][r];
      const int c = kt * 2 + (lg >> 1);  // 8-elem chunk index of key group
      *reinterpret_cast<bf16x4*>(&Pw[lr * 64 + ((c ^ (lr & 7)) << 3) + ((lg & 1) << 2)]) = pk;
    }

    // ---- O += P @ V ; l += P @ ones ----
    __builtin_amdgcn_s_setprio(1);
#pragma unroll
    for (int ks = 0; ks < 2; ++ks) {
      const int e = lr & 7;
      bf16x8 pa = load8(&Pw[lr * 64 + (((ks * 4 + lg) ^ e) << 3)]);
#pragma unroll
      for (int n = 0; n < 8; ++n) {
        bf16x8 vb = load8(&Vt[(n * 16 + lr) * 64 + (((ks * 4 + lg) ^ e) << 3)]);
        o[n] = mfma16x16(pa, vb, o[n]);
      }
      o8 = mfma16x16(pa, ones, o8);
    }
    __builtin_amdgcn_s_setprio(0);
    __syncthreads();
  }

  float linv[4];
#pragma unroll
  for (int r = 0; r < 4; ++r) linv[r] = __builtin_amdgcn_rcpf(o8[r]);
#pragma unroll
  for (int n = 0; n < 8; ++n)
#pragma unroll
    for (int r = 0; r < 4; ++r) {
      const int qr = qt * 64 + wid * 16 + lg * 4 + r;
      out[(size_t)(tokb + qr) * 2048 + h * 128 + n * 16 + lr] = (bf16_t)(o[n][r] * linv[r]);
    }
}

// ---------------- launch ----------------

extern "C" void kernel_launch(void* const* d_in, const int* in_sizes, int n_in, void* d_out,
                              int out_size, void* d_ws, size_t ws_size, hipStream_t stream) {
  const float* hs = (const float*)d_in[0];
  const float* Wqa = (const float*)d_in[1];
  const float* Wqb = (const float*)d_in[2];
  const float* Wkva = (const float*)d_in[3];
  const float* Wkvb = (const float*)d_in[4];
  const float* Wo = (const float*)d_in[5];
  float* out = (float*)d_out;

  char* ws = (char*)d_ws;
  size_t off = 0;
  auto alloc = [&](size_t bytes) {
    void* p = ws + off;
    off += (bytes + 255) & ~(size_t)255;
    return p;
  };
  bf16_t* hsb = (bf16_t*)alloc((size_t)NTOK * 2048 * 2);
  bf16_t* W1t = (bf16_t*)alloc((size_t)2176 * 2048 * 2);
  bf16_t* Wqbt = (bf16_t*)alloc((size_t)2048 * 1536 * 2);
  bf16_t* Wkvbt = (bf16_t*)alloc((size_t)3072 * 512 * 2);
  bf16_t* Wot = (bf16_t*)alloc((size_t)2048 * 2048 * 2);
  bf16_t* lat = (bf16_t*)alloc((size_t)NTOK * 2176 * 2);
  bf16_t* qb = (bf16_t*)alloc((size_t)NTOK * 2048 * 2);
  bf16_t* knb = (bf16_t*)alloc((size_t)NTOK * 1024 * 2);
  bf16_t* attn = (bf16_t*)alloc((size_t)NTOK * 2048 * 2);
  bf16_t* vT = (bf16_t*)alloc((size_t)32 * 128 * 2048 * 2);
  float* cosT = (float*)alloc((size_t)S_ * 32 * 4);
  float* sinT = (float*)alloc((size_t)S_ * 32 * 4);

  // merged prep: cast | rope tables | 5 weight transposes, one dispatch
  {
    TDesc5 ds;
    int o0 = 0;
    auto add = [&](int i, const float* src, bf16_t* dst, int K, int Nsrc, int Nout, int perm) {
      int bxc = Nout / 32, cnt = bxc * (K / 32);
      ds.d[i] = TDesc{src, dst, K, Nsrc, bxc, o0, perm};
      o0 += cnt;
    };
    add(0, Wqa, W1t, 2048, 1536, 1536, 0);
    add(1, Wkva, W1t + (size_t)1536 * 2048, 2048, 576, 640, 0);
    add(2, Wqb, Wqbt, 1536, 2048, 2048, 0);
    add(3, Wkvb, Wkvbt, 512, 3072, 3072, 1);
    add(4, Wo, Wot, 2048, 2048, 2048, 0);
    const int castB = (NTOK * 2048 / 4 + 255) / 256;  // 8192
    const int ropeB = (S_ * 32 + 255) / 256;          // 256
    prep_all_k<<<castB + ropeB + o0, 256, 0, stream>>>(hs, hsb, NTOK * 2048, cosT, sinT, ds,
                                                       castB, ropeB);
  }

  // lat = hsb @ [Wqa | Wkva(pad to 640)]  + fused k_pe RoPE
  gemm_lat_k<<<dim3(544), 256, 0, stream>>>(hsb, W1t, lat, cosT, sinT);
  // q (+RoPE, scaled) and kv (knb + vT) in one dispatch (role-interleaved)
  const float scale = 0.08838834764831845f * 1.4426950408889634f;  // 1/sqrt(128)*log2e
  gemm_qkv_k<<<dim3(1280), 256, 0, stream>>>(lat, Wqbt, Wkvbt, qb, knb, vT, cosT, sinT, scale);
  // attention (16x16 swapped-QK^T, single-buffered, R9 config)
  attn_fused<<<dim3(1024), 256, 0, stream>>>(qb, knb, lat, vT, attn);
  // out = attn @ Wo (f32 output)
  gemm_out_k<<<dim3(512), 256, 0, stream>>>(attn, Wot, out);
}

// Round 16
// 265.843 us; speedup vs baseline: 1.1767x; 1.0196x over previous
//
#include <hip/hip_runtime.h>
#include <hip/hip_bf16.h>
#include <cstdint>
#include <cstddef>

typedef __bf16 bf16_t;
typedef __attribute__((ext_vector_type(4))) __bf16 bf16x4;
typedef __attribute__((ext_vector_type(8))) __bf16 bf16x8;
typedef __attribute__((ext_vector_type(4))) float f32x4;

#define S_ 2048
#define H_ 16
#define NTOK 4096

__device__ __forceinline__ f32x4 mfma16x16(bf16x8 a, bf16x8 b, f32x4 c) {
  return __builtin_amdgcn_mfma_f32_16x16x32_bf16(a, b, c, 0, 0, 0);
}
__device__ __forceinline__ bf16x8 load8(const bf16_t* p) {
  return *reinterpret_cast<const bf16x8*>(p);
}
__device__ __forceinline__ void load_lds16(const void* g, void* l) {
  __builtin_amdgcn_global_load_lds(
      (const __attribute__((address_space(1))) uint32_t*)g,
      (__attribute__((address_space(3))) uint32_t*)l, 16, 0, 0);
}

// ---------------- merged prep kernel: cast | rope tables | 5x transpose ----------------
// Block-role dispatch: [0, castB) elementwise f32->bf16 cast of hidden_states;
// [castB, castB+ropeB) rope cos/sin tables; rest: weight transpose+cast jobs.
// perm==1 (Wkvb job): output row n maps to src col f(n) so the kv GEMM's N axis
// becomes [16*64 k_nope | 16*128 v]; per 32-col block the src stays contiguous.

struct TDesc {
  const float* src;
  bf16_t* dst;
  int K, Nsrc, bxc, off, perm;
};
struct TDesc5 {
  TDesc d[5];
};

__global__ void prep_all_k(const float* __restrict__ hs, bf16_t* __restrict__ hsb, int ncast,
                           float* __restrict__ cosT, float* __restrict__ sinT, TDesc5 ds,
                           int castB, int ropeB) {
  __shared__ float tile[32][33];
  int bid = blockIdx.x;

  if (bid < castB) {  // ---- cast hidden_states to bf16 ----
    int idx = bid * 256 + threadIdx.x;
    int i4 = idx * 4;
    if (i4 < ncast) {
      float4 v = *reinterpret_cast<const float4*>(hs + i4);
      hsb[i4 + 0] = (bf16_t)v.x;
      hsb[i4 + 1] = (bf16_t)v.y;
      hsb[i4 + 2] = (bf16_t)v.z;
      hsb[i4 + 3] = (bf16_t)v.w;
    }
    return;
  }
  bid -= castB;

  if (bid < ropeB) {  // ---- rope cos/sin tables ----
    int idx = bid * 256 + threadIdx.x;
    if (idx < S_ * 32) {
      int s = idx >> 5, i = idx & 31;
      float inv = powf(10000.0f, -(2.0f * (float)i) / 64.0f);
      float fr = (float)s * inv;
      cosT[idx] = cosf(fr);
      sinT[idx] = sinf(fr);
    }
    return;
  }
  bid -= ropeB;

  // ---- weight transpose+cast ----
  int i = 0;
#pragma unroll
  for (int j = 1; j < 5; ++j)
    if (bid >= ds.d[j].off) i = j;
  const float* __restrict__ in = ds.d[i].src;
  bf16_t* __restrict__ out = ds.d[i].dst;
  const int K = ds.d[i].K, Nsrc = ds.d[i].Nsrc;
  const int local = bid - ds.d[i].off;
  const int n0 = (local % ds.d[i].bxc) * 32;
  const int k0 = (local / ds.d[i].bxc) * 32;
  int srcn0 = n0;
  if (ds.d[i].perm) {
    srcn0 = (n0 < 1024) ? ((n0 >> 6) * 192 + (n0 & 63))
                        : (((n0 - 1024) >> 7) * 192 + 64 + ((n0 - 1024) & 127));
  }
  int tx = threadIdx.x & 31, ty = threadIdx.x >> 5;
#pragma unroll
  for (int r = 0; r < 4; ++r) {
    int k = k0 + ty + r * 8, n = srcn0 + tx;
    tile[ty + r * 8][tx] = (n < Nsrc) ? in[(size_t)k * Nsrc + n] : 0.0f;
  }
  __syncthreads();
#pragma unroll
  for (int r = 0; r < 4; ++r) {
    int n = n0 + ty + r * 8, k = k0 + tx;
    out[(size_t)n * K + k] = (bf16_t)tile[tx][ty + r * 8];
  }
}

// ---------------- GEMM loop: 128x128 tile, BK=64, chunk-XOR swizzle, 2-phase dbuf ----------------
// LDS[row][chunk] holds global[row][chunk ^ (row&7)]; staged via pre-swizzled global source.
// Pipeline: STAGE(t+1) issued BEFORE compute(t); counted s_waitcnt vmcnt(8) waits only for
// tile-t's 8 loads (issued one iteration earlier -> latency hidden under compute(t-1)).
// Raw s_barrier (NOT __syncthreads) so the compiler can't inject a vmcnt(0) drain.

__device__ __forceinline__ void gemm_loop64(const bf16_t* __restrict__ A, int lda,
                                            const bf16_t* __restrict__ Bt, int K, int m0, int n0,
                                            int tid, bf16_t* Al, bf16_t* Bl, f32x4 (&acc)[4][4]) {
  const int wid = tid >> 6, lane = tid & 63;
  const int wm = (wid >> 1) * 64, wn = (wid & 1) * 64;
  const int srow8 = lane >> 3, c8 = lane & 7;
  const int swz8 = c8 ^ srow8;
  const int lr = lane & 15, lg = lane >> 4;
  const int e = lr & 7;

  const bf16_t* ag = A + (size_t)(m0 + wid * 32 + srow8) * lda + (swz8 << 3);
  const bf16_t* bg = Bt + (size_t)(n0 + wid * 32 + srow8) * K + (swz8 << 3);

  auto STAGE = [&](int buf, int k0) {
    bf16_t* ab = Al + buf * (128 * 64);
    bf16_t* bb = Bl + buf * (128 * 64);
#pragma unroll
    for (int rr = 0; rr < 4; ++rr) {
      load_lds16(ag + (size_t)(rr * 8) * lda + k0, &ab[(wid * 32 + rr * 8) * 64]);
      load_lds16(bg + (size_t)(rr * 8) * K + k0, &bb[(wid * 32 + rr * 8) * 64]);
    }
  };

  STAGE(0, 0);
  int cur = 0;
  for (int k0 = 0; k0 < K; k0 += 64) {
    if (k0 + 64 < K) {
      STAGE(cur ^ 1, k0 + 64);  // 8 new vmem ops into the other buffer
      __builtin_amdgcn_sched_barrier(0);
      asm volatile("s_waitcnt vmcnt(8)" ::: "memory");  // wait only for tile-t's 8
    } else {
      asm volatile("s_waitcnt vmcnt(0)" ::: "memory");  // last tile: full drain
    }
    __builtin_amdgcn_sched_barrier(0);
    __builtin_amdgcn_s_barrier();  // all waves' tile-t loads landed
    __builtin_amdgcn_sched_barrier(0);
    const bf16_t* Ab = Al + cur * (128 * 64);
    const bf16_t* Bb = Bl + cur * (128 * 64);
#pragma unroll
    for (int kk = 0; kk < 2; ++kk) {
      bf16x8 af[4], bfr[4];
#pragma unroll
      for (int i = 0; i < 4; ++i) {
        af[i] = load8(&Ab[(wm + i * 16 + lr) * 64 + (((kk * 4 + lg) ^ e) << 3)]);
        bfr[i] = load8(&Bb[(wn + i * 16 + lr) * 64 + (((kk * 4 + lg) ^ e) << 3)]);
      }
#pragma unroll
      for (int i = 0; i < 4; ++i)
#pragma unroll
        for (int j = 0; j < 4; ++j) acc[i][j] = mfma16x16(af[i], bfr[j], acc[i][j]);
    }
    __builtin_amdgcn_sched_barrier(0);
    __builtin_amdgcn_s_barrier();  // all waves done reading buf cur (reads retired via lgkmcnt)
    cur ^= 1;
  }
}

// ---------------- lat GEMM: lat = hsb @ [Wqa | Wkva(pad)] + fused k_pe RoPE ----------------
// 544 blocks (XCD-swizzled). C: [4096][2176]; cols 2048..2111 get RoPE.

__global__ __launch_bounds__(256) void gemm_lat_k(const bf16_t* __restrict__ A,
                                                  const bf16_t* __restrict__ Bt,
                                                  bf16_t* __restrict__ C,
                                                  const float* __restrict__ cosT,
                                                  const float* __restrict__ sinT) {
  __shared__ alignas(16) bf16_t Al[2 * 128 * 64];
  __shared__ alignas(16) bf16_t Bl[2 * 128 * 64];
  const int tid = threadIdx.x;
  const int sw = (blockIdx.x & 7) * 68 + (blockIdx.x >> 3);  // 544 = 8*68
  const int m0 = (sw / 17) * 128, n0 = (sw % 17) * 128;
  f32x4 acc[4][4] = {};
  gemm_loop64(A, 2048, Bt, 2048, m0, n0, tid, Al, Bl, acc);

  const int wid = tid >> 6, lane = tid & 63;
  const int wm = (wid >> 1) * 64, wn = (wid & 1) * 64;
  const int lr = lane & 15, lg = lane >> 4;
  const bool rope = (n0 == 2048) && (wn == 0);
  const int ir_base = lr >> 1;  // with j: ir = (j*16+lr)>>1 = j*8 + (lr>>1)
  const bool odd = lane & 1;
#pragma unroll
  for (int i = 0; i < 4; ++i)
#pragma unroll
    for (int j = 0; j < 4; ++j) {
      float v4[4];
#pragma unroll
      for (int r = 0; r < 4; ++r) v4[r] = acc[i][j][r];
      if (rope) {
        const int ir = j * 8 + ir_base;
#pragma unroll
        for (int r = 0; r < 4; ++r) {
          const int srow_ = (m0 + wm + i * 16 + lg * 4 + r) & (S_ - 1);
          float c = cosT[srow_ * 32 + ir], sn = sinT[srow_ * 32 + ir];
          float partner = __shfl_xor(v4[r], 1);
          v4[r] = odd ? (v4[r] * c + partner * sn) : (v4[r] * c - partner * sn);
        }
      }
#pragma unroll
      for (int r = 0; r < 4; ++r) {
        int row = m0 + wm + i * 16 + lg * 4 + r;
        int col = n0 + wn + j * 16 + lr;
        C[(size_t)row * 2176 + col] = (bf16_t)v4[r];
      }
    }
}

// ---------------- fused q-GEMM + kv-GEMM (one dispatch, 1280 blocks XCD-swizzled) ----------------
// role interleaved: q when sw%5<2 (512 q-blocks, 24 K-steps) else kv (768 blocks, 8 K-steps).
// q:  lat[:, :1536] @ Wqbt, scaled, fused q RoPE (wn==64 waves) -> qb [4096][2048]
// kv: lat[:, 1536:] @ Wkvbt(permuted): n0<1024 -> knb (k_nope); else vT (v transposed)

__global__ __launch_bounds__(256) void gemm_qkv_k(const bf16_t* __restrict__ lat,
                                                  const bf16_t* __restrict__ Wqbt,
                                                  const bf16_t* __restrict__ Wkvbt,
                                                  bf16_t* __restrict__ qb,
                                                  bf16_t* __restrict__ knb,
                                                  bf16_t* __restrict__ vT,
                                                  const float* __restrict__ cosT,
                                                  const float* __restrict__ sinT, float qscale) {
  __shared__ alignas(16) bf16_t Al[2 * 128 * 64];
  __shared__ alignas(16) bf16_t Bl[2 * 128 * 64];
  const int tid = threadIdx.x;
  const int sw = (blockIdx.x & 7) * 160 + (blockIdx.x >> 3);  // 1280 = 8*160
  const int wid = tid >> 6, lane = tid & 63;
  const int wm = (wid >> 1) * 64, wn = (wid & 1) * 64;
  const int lr = lane & 15, lg = lane >> 4;
  f32x4 acc[4][4] = {};
  const int r5 = sw % 5, q5 = sw / 5;

  if (r5 < 2) {
    const int qi = q5 * 2 + r5;  // 0..511
    const int m0 = (qi >> 4) * 128, n0 = (qi & 15) * 128;
    gemm_loop64(lat, 2176, Wqbt, 1536, m0, n0, tid, Al, Bl, acc);
    const bool rope = (wn == 64);  // d = wn + j*16 + lr; rope iff d >= 64
    const int ir_base = lr >> 1;
    const bool odd = lane & 1;
#pragma unroll
    for (int i = 0; i < 4; ++i)
#pragma unroll
      for (int j = 0; j < 4; ++j) {
        float v4[4];
#pragma unroll
        for (int r = 0; r < 4; ++r) v4[r] = acc[i][j][r] * qscale;
        if (rope) {
          const int ir = j * 8 + ir_base;
#pragma unroll
          for (int r = 0; r < 4; ++r) {
            const int srow_ = (m0 + wm + i * 16 + lg * 4 + r) & (S_ - 1);
            float c = cosT[srow_ * 32 + ir], sn = sinT[srow_ * 32 + ir];
            float partner = __shfl_xor(v4[r], 1);
            v4[r] = odd ? (v4[r] * c + partner * sn) : (v4[r] * c - partner * sn);
          }
        }
#pragma unroll
        for (int r = 0; r < 4; ++r) {
          int row = m0 + wm + i * 16 + lg * 4 + r;
          int col = n0 + wn + j * 16 + lr;
          qb[(size_t)row * 2048 + col] = (bf16_t)v4[r];
        }
      }
  } else {
    const int ki = q5 * 3 + (r5 - 2);  // 0..767
    const int m0 = (ki / 24) * 128, n0 = (ki % 24) * 128;
    gemm_loop64(lat + 1536, 2176, Wkvbt, 512, m0, n0, tid, Al, Bl, acc);
    if (n0 < 1024) {  // k_nope -> knb
#pragma unroll
      for (int i = 0; i < 4; ++i)
#pragma unroll
        for (int j = 0; j < 4; ++j)
#pragma unroll
          for (int r = 0; r < 4; ++r) {
            int row = m0 + wm + i * 16 + lg * 4 + r;
            int col = n0 + wn + j * 16 + lr;
            knb[(size_t)row * 1024 + col] = (bf16_t)acc[i][j][r];
          }
    } else {  // v -> vT, 4 consecutive tokens packed per store
#pragma unroll
      for (int i = 0; i < 4; ++i) {
        const int row0 = m0 + wm + i * 16 + lg * 4;
        const int bb = row0 >> 11;       // batch
        const int s0 = row0 & (S_ - 1);  // seq pos (multiple of 4)
#pragma unroll
        for (int j = 0; j < 4; ++j) {
          const int idx = n0 + wn + j * 16 + lr - 1024;
          const int h = idx >> 7, d = idx & 127;
          bf16x4 pk;
#pragma unroll
          for (int r = 0; r < 4; ++r) pk[r] = (bf16_t)acc[i][j][r];
          *reinterpret_cast<bf16x4*>(&vT[((size_t)(bb * 16 + h) * 128 + d) * 2048 + s0]) = pk;
        }
      }
    }
  }
}

// ---------------- out GEMM: out = attn @ Wo (f32 output, 512 blocks XCD-swizzled) ----------------

__global__ __launch_bounds__(256) void gemm_out_k(const bf16_t* __restrict__ A,
                                                  const bf16_t* __restrict__ Bt,
                                                  float* __restrict__ C) {
  __shared__ alignas(16) bf16_t Al[2 * 128 * 64];
  __shared__ alignas(16) bf16_t Bl[2 * 128 * 64];
  const int tid = threadIdx.x;
  const int sw = (blockIdx.x & 7) * 64 + (blockIdx.x >> 3);  // 512 = 8*64
  const int m0 = (sw >> 4) * 128, n0 = (sw & 15) * 128;
  f32x4 acc[4][4] = {};
  gemm_loop64(A, 2048, Bt, 2048, m0, n0, tid, Al, Bl, acc);
  const int wid = tid >> 6, lane = tid & 63;
  const int wm = (wid >> 1) * 64, wn = (wid & 1) * 64;
  const int lr = lane & 15, lg = lane >> 4;
#pragma unroll
  for (int i = 0; i < 4; ++i)
#pragma unroll
    for (int j = 0; j < 4; ++j)
#pragma unroll
      for (int r = 0; r < 4; ++r) {
        int row = m0 + wm + i * 16 + lg * 4 + r;
        int col = n0 + wn + j * 16 + lr;
        C[(size_t)row * 2048 + col] = acc[i][j][r];
      }
}

// ---------------- fused causal flash attention (swapped-QK^T, LPT block order) ----------------
// q:   [4096][2048] bf16 (pre-scaled by log2e/sqrt(128), q_pe roped)  col = h*128 + d
// knb: [4096][1024] bf16  col = h*64 + c (k_nope)
// lat: [4096][2176] bf16  cols 2048..2111 = roped k_pe (shared across heads)
// vT:  [32][128][2048] bf16  (V transposed per (b,h))
// out: [4096][2048] bf16  col = h*128 + d
//
// QK^T computed as mfma(K, Q) -> S^T tile: lane (lr,lg) reg r = S[qrow=lr][key=kt*16+lg*4+r].
// LPT dispatch order: qt = 31 - (bid>>5) -> longest blocks (qt=31, 32 key-tiles) launch
// first, shortest fill the drain tail (block duration ~ qt+1; HW dispatches in bid order).
__global__ __launch_bounds__(256) void attn_fused(const bf16_t* __restrict__ q,
                                                  const bf16_t* __restrict__ knb,
                                                  const bf16_t* __restrict__ lat,
                                                  const bf16_t* __restrict__ vT,
                                                  bf16_t* __restrict__ out) {
  __shared__ alignas(16) bf16_t Kn[64 * 64];
  __shared__ alignas(16) bf16_t Kp[64 * 64];
  __shared__ alignas(16) bf16_t Vt[128 * 64];
  __shared__ alignas(16) bf16_t Pl[4][16 * 64];
  const int tid = threadIdx.x, wid = tid >> 6, lane = tid & 63;
  const int bid = blockIdx.x;
  const int qt = 31 - (bid >> 5);  // LPT: longest first
  const int bh = bid & 31;
  const int b = bh >> 4, h = bh & 15;
  const int tokb = b * S_;
  const int lr = lane & 15, lg = lane >> 4;
  const int srow8 = lane >> 3, c8 = lane & 7;
  const int swz8 = c8 ^ srow8;  // swizzled chunk for staging source
  bf16_t* Pw = &Pl[wid][0];

  bf16x8 ones;
#pragma unroll
  for (int j = 0; j < 8; ++j) ones[j] = (bf16_t)1.0f;

  bf16x8 qf[4];
  {
    const int qrow = qt * 64 + wid * 16 + lr;
    const bf16_t* qp = q + (size_t)(tokb + qrow) * 2048 + h * 128 + lg * 8;
#pragma unroll
    for (int ds = 0; ds < 4; ++ds) qf[ds] = load8(qp + ds * 32);
  }

  f32x4 o[8] = {};
  f32x4 o8 = {};     // row-sums of P (softmax denominator), via matrix pipe
  float m = -1e30f;  // running max of row qrow=lr (one per lane)
  const int qr_glob = qt * 64 + wid * 16 + lr;

  for (int t = 0; t <= qt; ++t) {
    const int kb = t * 64;
#pragma unroll
    for (int rr = 0; rr < 2; ++rr) {
      const int r0 = wid * 16 + rr * 8;
      const size_t tk = (size_t)(tokb + kb + r0 + srow8);
      load_lds16(knb + tk * 1024 + h * 64 + (swz8 << 3), &Kn[r0 * 64]);
      load_lds16(lat + tk * 2176 + 2048 + (swz8 << 3), &Kp[r0 * 64]);
    }
#pragma unroll
    for (int rr = 0; rr < 4; ++rr) {
      const int r0 = wid * 32 + rr * 8;
      load_lds16(vT + ((size_t)bh * 128 + r0 + srow8) * 2048 + kb + (swz8 << 3), &Vt[r0 * 64]);
    }
    __syncthreads();

    // ---- S^T = K Q^T : lane (lr,lg) reg r = S[qrow=lr][key=kt*16+lg*4+r] ----
    f32x4 s[4];
    __builtin_amdgcn_s_setprio(1);
#pragma unroll
    for (int kt = 0; kt < 4; ++kt) {
      const int row = kt * 16 + lr;
      const int e = lr & 7;
      bf16x8 kf0 = load8(&Kn[row * 64 + ((lg ^ e) << 3)]);
      bf16x8 kf1 = load8(&Kn[row * 64 + (((lg + 4) ^ e) << 3)]);
      bf16x8 kf2 = load8(&Kp[row * 64 + ((lg ^ e) << 3)]);
      bf16x8 kf3 = load8(&Kp[row * 64 + (((lg + 4) ^ e) << 3)]);
      f32x4 acc = {0.f, 0.f, 0.f, 0.f};
      acc = mfma16x16(kf0, qf[0], acc);  // swapped: A=K, B=Q -> S^T
      acc = mfma16x16(kf1, qf[1], acc);
      acc = mfma16x16(kf2, qf[2], acc);
      acc = mfma16x16(kf3, qf[3], acc);
      s[kt] = acc;
    }
    __builtin_amdgcn_s_setprio(0);

    if (t == qt) {  // causal mask on diagonal tile
#pragma unroll
      for (int kt = 0; kt < 4; ++kt)
#pragma unroll
        for (int r = 0; r < 4; ++r) {
          const int key = kb + kt * 16 + lg * 4 + r;
          if (key > qr_glob) s[kt][r] = -1e30f;
        }
    }

    // ---- online softmax (exp2 domain, defer-max THR=8), per-lane row ----
    float tm;
    {
      float a0 = fmaxf(fmaxf(s[0][0], s[0][1]), fmaxf(s[0][2], s[0][3]));
      float a1 = fmaxf(fmaxf(s[1][0], s[1][1]), fmaxf(s[1][2], s[1][3]));
      float a2 = fmaxf(fmaxf(s[2][0], s[2][1]), fmaxf(s[2][2], s[2][3]));
      float a3 = fmaxf(fmaxf(s[3][0], s[3][1]), fmaxf(s[3][2], s[3][3]));
      tm = fmaxf(fmaxf(a0, a1), fmaxf(a2, a3));
      tm = fmaxf(tm, __shfl_xor(tm, 16));
      tm = fmaxf(tm, __shfl_xor(tm, 32));
    }
    if (!__all(tm - m <= 8.0f)) {
      float mn = fmaxf(m, tm);
      float corr = exp2f(m - mn);
      m = mn;
      float corrv[4];
#pragma unroll
      for (int r = 0; r < 4; ++r) corrv[r] = __shfl(corr, lg * 4 + r);
#pragma unroll
      for (int r = 0; r < 4; ++r) {
        o8[r] *= corrv[r];
#pragma unroll
        for (int n = 0; n < 8; ++n) o[n][r] *= corrv[r];
      }
    }
#pragma unroll
    for (int kt = 0; kt < 4; ++kt)
#pragma unroll
      for (int r = 0; r < 4; ++r) s[kt][r] = exp2f(s[kt][r] - m);

    // ---- stage P: 4 consecutive keys per reg group -> bf16x4 b64 writes (swizzled) ----
#pragma unroll
    for (int kt = 0; kt < 4; ++kt) {
      bf16x4 pk;
#pragma unroll
      for (int r = 0; r < 4; ++r) pk[r] = (bf16_t)s[kt][r];
      const int c = kt * 2 + (lg >> 1);  // 8-elem chunk index of key group
      *reinterpret_cast<bf16x4*>(&Pw[lr * 64 + ((c ^ (lr & 7)) << 3) + ((lg & 1) << 2)]) = pk;
    }

    // ---- O += P @ V ; l += P @ ones ----
    __builtin_amdgcn_s_setprio(1);
#pragma unroll
    for (int ks = 0; ks < 2; ++ks) {
      const int e = lr & 7;
      bf16x8 pa = load8(&Pw[lr * 64 + (((ks * 4 + lg) ^ e) << 3)]);
#pragma unroll
      for (int n = 0; n < 8; ++n) {
        bf16x8 vb = load8(&Vt[(n * 16 + lr) * 64 + (((ks * 4 + lg) ^ e) << 3)]);
        o[n] = mfma16x16(pa, vb, o[n]);
      }
      o8 = mfma16x16(pa, ones, o8);
    }
    __builtin_amdgcn_s_setprio(0);
    __syncthreads();
  }

  float linv[4];
#pragma unroll
  for (int r = 0; r < 4; ++r) linv[r] = __builtin_amdgcn_rcpf(o8[r]);
#pragma unroll
  for (int n = 0; n < 8; ++n)
#pragma unroll
    for (int r = 0; r < 4; ++r) {
      const int qr = qt * 64 + wid * 16 + lg * 4 + r;
      out[(size_t)(tokb + qr) * 2048 + h * 128 + n * 16 + lr] = (bf16_t)(o[n][r] * linv[r]);
    }
}

// ---------------- launch ----------------

extern "C" void kernel_launch(void* const* d_in, const int* in_sizes, int n_in, void* d_out,
                              int out_size, void* d_ws, size_t ws_size, hipStream_t stream) {
  const float* hs = (const float*)d_in[0];
  const float* Wqa = (const float*)d_in[1];
  const float* Wqb = (const float*)d_in[2];
  const float* Wkva = (const float*)d_in[3];
  const float* Wkvb = (const float*)d_in[4];
  const float* Wo = (const float*)d_in[5];
  float* out = (float*)d_out;

  char* ws = (char*)d_ws;
  size_t off = 0;
  auto alloc = [&](size_t bytes) {
    void* p = ws + off;
    off += (bytes + 255) & ~(size_t)255;
    return p;
  };
  bf16_t* hsb = (bf16_t*)alloc((size_t)NTOK * 2048 * 2);
  bf16_t* W1t = (bf16_t*)alloc((size_t)2176 * 2048 * 2);
  bf16_t* Wqbt = (bf16_t*)alloc((size_t)2048 * 1536 * 2);
  bf16_t* Wkvbt = (bf16_t*)alloc((size_t)3072 * 512 * 2);
  bf16_t* Wot = (bf16_t*)alloc((size_t)2048 * 2048 * 2);
  bf16_t* lat = (bf16_t*)alloc((size_t)NTOK * 2176 * 2);
  bf16_t* qb = (bf16_t*)alloc((size_t)NTOK * 2048 * 2);
  bf16_t* knb = (bf16_t*)alloc((size_t)NTOK * 1024 * 2);
  bf16_t* attn = (bf16_t*)alloc((size_t)NTOK * 2048 * 2);
  bf16_t* vT = (bf16_t*)alloc((size_t)32 * 128 * 2048 * 2);
  float* cosT = (float*)alloc((size_t)S_ * 32 * 4);
  float* sinT = (float*)alloc((size_t)S_ * 32 * 4);

  // merged prep: cast | rope tables | 5 weight transposes, one dispatch
  {
    TDesc5 ds;
    int o0 = 0;
    auto add = [&](int i, const float* src, bf16_t* dst, int K, int Nsrc, int Nout, int perm) {
      int bxc = Nout / 32, cnt = bxc * (K / 32);
      ds.d[i] = TDesc{src, dst, K, Nsrc, bxc, o0, perm};
      o0 += cnt;
    };
    add(0, Wqa, W1t, 2048, 1536, 1536, 0);
    add(1, Wkva, W1t + (size_t)1536 * 2048, 2048, 576, 640, 0);
    add(2, Wqb, Wqbt, 1536, 2048, 2048, 0);
    add(3, Wkvb, Wkvbt, 512, 3072, 3072, 1);
    add(4, Wo, Wot, 2048, 2048, 2048, 0);
    const int castB = (NTOK * 2048 / 4 + 255) / 256;  // 8192
    const int ropeB = (S_ * 32 + 255) / 256;          // 256
    prep_all_k<<<castB + ropeB + o0, 256, 0, stream>>>(hs, hsb, NTOK * 2048, cosT, sinT, ds,
                                                       castB, ropeB);
  }

  // lat = hsb @ [Wqa | Wkva(pad to 640)]  + fused k_pe RoPE
  gemm_lat_k<<<dim3(544), 256, 0, stream>>>(hsb, W1t, lat, cosT, sinT);
  // q (+RoPE, scaled) and kv (knb + vT) in one dispatch (role-interleaved)
  const float scale = 0.08838834764831845f * 1.4426950408889634f;  // 1/sqrt(128)*log2e
  gemm_qkv_k<<<dim3(1280), 256, 0, stream>>>(lat, Wqbt, Wkvbt, qb, knb, vT, cosT, sinT, scale);
  // attention (16x16 swapped-QK^T, LPT order)
  attn_fused<<<dim3(1024), 256, 0, stream>>>(qb, knb, lat, vT, attn);
  // out = attn @ Wo (f32 output)
  gemm_out_k<<<dim3(512), 256, 0, stream>>>(attn, Wot, out);
}